// Round 2
// baseline (2009.703 us; speedup 1.0000x reference)
//
#include <hip/hip_runtime.h>
#include <stdint.h>

#define DIM 2048
#define HID 5632
#define SEQ 8192
#define NW3 (3*HID)            // 16896
#define CONV 4
#define QROWS 2048             // rows per streamed quarter
#define NQ (SEQ/QROWS)         // 4
#define CHUNK 64
#define NCHUNKQ (QROWS/CHUNK)  // 32

typedef __attribute__((ext_vector_type(8))) __bf16 bf16x8;
typedef __attribute__((ext_vector_type(4))) float f32x4;

__device__ __forceinline__ uint16_t f2bf(float f) {
  union { float f; uint32_t u; } v; v.f = f;
  return (uint16_t)((v.u + 0x7FFFu + ((v.u >> 16) & 1u)) >> 16);
}
__device__ __forceinline__ float bf2f(uint16_t h) {
  union { uint32_t u; float f; } v; v.u = ((uint32_t)h) << 16;
  return v.f;
}

// ---------------- fp32 -> bf16 conversion (vectorized x4) ----------------
__global__ void cvt4_kernel(const float* __restrict__ src, uint16_t* __restrict__ dst, int n4) {
  int i = blockIdx.x * blockDim.x + threadIdx.x;
  if (i >= n4) return;
  float4 v = ((const float4*)src)[i];
  ushort4 o;
  o.x = f2bf(v.x); o.y = f2bf(v.y); o.z = f2bf(v.z); o.w = f2bf(v.w);
  ((ushort4*)dst)[i] = o;
}

// ---------------- m97-style bf16 GEMM: C = A(M,K;lda) * B(N,K;ldb)^T ----------------
__device__ __forceinline__ void load_lds16(const void* g, void* l) {
  __builtin_amdgcn_global_load_lds(
      (__attribute__((address_space(1))) void*)g,
      (__attribute__((address_space(3))) void*)l, 16, 0, 0);
}

template<bool OUT_BF16>
__global__ __launch_bounds__(256)
void gemm_bt(const uint16_t* __restrict__ A, int lda,
             const uint16_t* __restrict__ B, int ldb,
             void* __restrict__ C, int ldc, int K)
{
  __shared__ uint16_t As[128*32];
  __shared__ uint16_t Bs[128*32];
  const int tid  = threadIdx.x;
  const int wave = tid >> 6;
  const int lane = tid & 63;
  const int row0 = blockIdx.y * 128;
  const int col0 = blockIdx.x * 128;
  const int wm = (wave & 1) * 64;
  const int wn = (wave >> 1) * 64;

  f32x4 acc[4][4];
  #pragma unroll
  for (int i=0;i<4;i++)
    #pragma unroll
    for (int j=0;j<4;j++) acc[i][j] = (f32x4){0.f,0.f,0.f,0.f};

  // staging map: lds elem = (wave*2+q)*512 + lane*8 holds row m=(wave*32+q*16+lane/4), k=(lane%4)*8..+8
  const int mA0 = wave*32 + (lane >> 2);
  const int kkl = (lane & 3) * 8;
  const int kq  = (lane >> 4) * 8;
  const int rm  = lane & 15;

  for (int k0 = 0; k0 < K; k0 += 32) {
    __syncthreads();
    #pragma unroll
    for (int q = 0; q < 2; ++q) {
      int m = mA0 + q*16;
      load_lds16(A + (size_t)(row0 + m)*lda + k0 + kkl, &As[(size_t)(wave*2+q)*512]);
      load_lds16(B + (size_t)(col0 + m)*ldb + k0 + kkl, &Bs[(size_t)(wave*2+q)*512]);
    }
    __syncthreads();
    bf16x8 af[4], bfr[4];
    #pragma unroll
    for (int i=0;i<4;i++) {
      af[i]  = *(const bf16x8*)&As[(wm + i*16 + rm)*32 + kq];
      bfr[i] = *(const bf16x8*)&Bs[(wn + i*16 + rm)*32 + kq];
    }
    #pragma unroll
    for (int i=0;i<4;i++)
      #pragma unroll
      for (int j=0;j<4;j++)
        acc[i][j] = __builtin_amdgcn_mfma_f32_16x16x32_bf16(af[i], bfr[j], acc[i][j], 0, 0, 0);
  }

  const int cr = (lane >> 4) * 4;  // C/D: col = lane&15, row = (lane>>4)*4 + reg
  const int cc = lane & 15;
  #pragma unroll
  for (int i=0;i<4;i++)
    #pragma unroll
    for (int j=0;j<4;j++) {
      int rb = row0 + wm + i*16 + cr;
      int c  = col0 + wn + j*16 + cc;
      #pragma unroll
      for (int r=0;r<4;r++) {
        float v = acc[i][j][r];
        if (OUT_BF16) ((uint16_t*)C)[(size_t)(rb+r)*ldc + c] = f2bf(v);
        else          ((float*)C)[(size_t)(rb+r)*ldc + c] = v;
      }
    }
}

// ---------------- segment helpers ----------------
// Gq layout per local row r (stride NW3): [0,HID)=w0, [HID,2HID)=z_pre, [2HID,3HID)=tilde_h

__device__ __forceinline__ void seg_info(const int* cuv, int ns, int t, int& ss, bool& st) {
  ss = 0; st = false;
  for (int i=0;i<ns;i++) { int cv = cuv[i]; if (cv<=t && cv>ss) ss=cv; if (cv==t) st=true; }
}

// ---------------- scan pass A: per-chunk conv+sigmoid+local scan ----------------
__global__ void scan_chunk(const uint16_t* __restrict__ Gq, int qstart,
                           const uint16_t* __restrict__ zprev,
                           const float* __restrict__ convw,
                           const int* __restrict__ cu, int ncu,
                           float* __restrict__ Ach, float* __restrict__ Bch)
{
  int h = blockIdx.x * blockDim.x + threadIdx.x;
  int c = blockIdx.y;
  if (h >= HID) return;
  const uint16_t* Z  = Gq + HID;
  const uint16_t* TH = Gq + 2*HID;
  float w0c = convw[h*4+0], w1c = convw[h*4+1], w2c = convw[h*4+2], w3c = convw[h*4+3];
  int cuv[8];
  int ns = ncu - 1; if (ns > 8) ns = 8;
  for (int i=0;i<ns;i++) cuv[i] = cu[i];
  int r0 = c * CHUNK;
  int t0 = qstart + r0;
  float z1, z2, z3;
  if (c == 0) {
    z1 = (t0-1 >= 0) ? bf2f(zprev[2*HID + h]) : 0.f;
    z2 = (t0-2 >= 0) ? bf2f(zprev[1*HID + h]) : 0.f;
    z3 = (t0-3 >= 0) ? bf2f(zprev[0*HID + h]) : 0.f;
  } else {
    z1 = bf2f(Z[(size_t)(r0-1)*NW3 + h]);
    z2 = bf2f(Z[(size_t)(r0-2)*NW3 + h]);
    z3 = bf2f(Z[(size_t)(r0-3)*NW3 + h]);
  }
  float Aacc = 1.f, Bacc = 0.f;
  for (int r = r0; r < r0 + CHUNK; ++r) {
    int t = qstart + r;
    float z0 = bf2f(Z[(size_t)r*NW3 + h]);
    float th = bf2f(TH[(size_t)r*NW3 + h]);
    int ss; bool st;
    seg_info(cuv, ns, t, ss, st);
    float s = z0*w3c;
    if (t-1 >= ss) s += z1*w2c;
    if (t-2 >= ss) s += z2*w1c;
    if (t-3 >= ss) s += z3*w0c;
    float zc = 1.f/(1.f + __expf(-s));
    float a = st ? 0.f : (1.f - zc);
    float b = zc * th;
    Aacc *= a;
    Bacc = a*Bacc + b;
    z3 = z2; z2 = z1; z1 = z0;
  }
  Ach[(size_t)c*HID + h] = Aacc;
  Bch[(size_t)c*HID + h] = Bacc;
}

// ---------------- scan pass B: combine chunk pairs, carry state across quarters ----------------
__global__ void scan_combine(const float* __restrict__ Ach, const float* __restrict__ Bch,
                             float* __restrict__ Hin, float* __restrict__ Sc, int first)
{
  int h = blockIdx.x * blockDim.x + threadIdx.x;
  if (h >= HID) return;
  float s = first ? 0.f : Sc[h];
  for (int c = 0; c < NCHUNKQ; ++c) {
    Hin[(size_t)c*HID + h] = s;
    s = Ach[(size_t)c*HID + h]*s + Bch[(size_t)c*HID + h];
  }
  Sc[h] = s;
}

// ---------------- scan pass C: fixup + h*silu(w0), hh written in place over TH ----------------
__global__ void scan_final(uint16_t* __restrict__ Gq, int qstart,
                           const uint16_t* __restrict__ zprev,
                           const float* __restrict__ convw,
                           const int* __restrict__ cu, int ncu,
                           const float* __restrict__ Hin)
{
  int h = blockIdx.x * blockDim.x + threadIdx.x;
  int c = blockIdx.y;
  if (h >= HID) return;
  const uint16_t* W0 = Gq;
  const uint16_t* Z  = Gq + HID;
  uint16_t*       TH = Gq + 2*HID;     // read th, then overwrite with hh
  float w0c = convw[h*4+0], w1c = convw[h*4+1], w2c = convw[h*4+2], w3c = convw[h*4+3];
  int cuv[8];
  int ns = ncu - 1; if (ns > 8) ns = 8;
  for (int i=0;i<ns;i++) cuv[i] = cu[i];
  int r0 = c * CHUNK;
  int t0 = qstart + r0;
  float z1, z2, z3;
  if (c == 0) {
    z1 = (t0-1 >= 0) ? bf2f(zprev[2*HID + h]) : 0.f;
    z2 = (t0-2 >= 0) ? bf2f(zprev[1*HID + h]) : 0.f;
    z3 = (t0-3 >= 0) ? bf2f(zprev[0*HID + h]) : 0.f;
  } else {
    z1 = bf2f(Z[(size_t)(r0-1)*NW3 + h]);
    z2 = bf2f(Z[(size_t)(r0-2)*NW3 + h]);
    z3 = bf2f(Z[(size_t)(r0-3)*NW3 + h]);
  }
  float state = Hin[(size_t)c*HID + h];
  for (int r = r0; r < r0 + CHUNK; ++r) {
    int t = qstart + r;
    float z0 = bf2f(Z[(size_t)r*NW3 + h]);
    float th = bf2f(TH[(size_t)r*NW3 + h]);
    int ss; bool st;
    seg_info(cuv, ns, t, ss, st);
    float s = z0*w3c;
    if (t-1 >= ss) s += z1*w2c;
    if (t-2 >= ss) s += z2*w1c;
    if (t-3 >= ss) s += z3*w0c;
    float zc = 1.f/(1.f + __expf(-s));
    float a = st ? 0.f : (1.f - zc);
    float b = zc * th;
    state = a*state + b;
    float w0v = bf2f(W0[(size_t)r*NW3 + h]);
    float silu = w0v / (1.f + __expf(-w0v));
    TH[(size_t)r*NW3 + h] = f2bf(state * silu);
    z3 = z2; z2 = z1; z1 = z0;
  }
}

// ---------------- save last 3 z-rows of this quarter for next quarter's conv taps ----------------
__global__ void save_ztail(const uint16_t* __restrict__ Gq, uint16_t* __restrict__ zprev) {
  int i = blockIdx.x * blockDim.x + threadIdx.x;
  if (i >= 3*HID) return;
  int j = i / HID;        // 0,1,2 -> rows QROWS-3+j
  int h = i - j*HID;
  zprev[i] = Gq[(size_t)(QROWS-3+j)*NW3 + HID + h];
}

// ---------------- launcher ----------------
extern "C" void kernel_launch(void* const* d_in, const int* in_sizes, int n_in,
                              void* d_out, int out_size, void* d_ws, size_t ws_size,
                              hipStream_t stream) {
  const float* x     = (const float*)d_in[0];
  const int*   cu    = (const int*)d_in[1];
  const float* w_w   = (const float*)d_in[2];
  const float* wz_w  = (const float*)d_in[3];
  const float* wh_w  = (const float*)d_in[4];
  const float* wo_w  = (const float*)d_in[5];
  const float* convw = (const float*)d_in[6];
  const int ncu = in_sizes[1];
  float* out = (float*)d_out;

  // workspace layout (~197 MB total)
  char* p = (char*)d_ws;
  uint16_t* xb    = (uint16_t*)p; p += (size_t)SEQ*DIM*2;        // 33.5 MB
  uint16_t* w3b   = (uint16_t*)p; p += (size_t)NW3*DIM*2;        // 69.2 MB
  uint16_t* wob   = (uint16_t*)p; p += (size_t)DIM*HID*2;        // 23.1 MB
  uint16_t* Gq    = (uint16_t*)p; p += (size_t)QROWS*NW3*2;      // 69.2 MB
  float* Ach  = (float*)p; p += (size_t)NCHUNKQ*HID*4;           // 0.72 MB
  float* Bch  = (float*)p; p += (size_t)NCHUNKQ*HID*4;
  float* Hin  = (float*)p; p += (size_t)NCHUNKQ*HID*4;
  float* Sc   = (float*)p; p += (size_t)HID*4;                   // 22.5 KB
  uint16_t* zprev = (uint16_t*)p; p += (size_t)3*HID*2;          // 34 KB

  // fp32 -> bf16 conversions
  {
    int n4;
    n4 = SEQ*DIM/4;  cvt4_kernel<<<(n4+255)/256, 256, 0, stream>>>(x, xb, n4);
    n4 = HID*DIM/4;  cvt4_kernel<<<(n4+255)/256, 256, 0, stream>>>(w_w,  w3b, n4);
                     cvt4_kernel<<<(n4+255)/256, 256, 0, stream>>>(wz_w, w3b + (size_t)HID*DIM, n4);
                     cvt4_kernel<<<(n4+255)/256, 256, 0, stream>>>(wh_w, w3b + (size_t)2*HID*DIM, n4);
    n4 = DIM*HID/4;  cvt4_kernel<<<(n4+255)/256, 256, 0, stream>>>(wo_w, wob, n4);
  }

  for (int q = 0; q < NQ; ++q) {
    const int qstart = q * QROWS;
    // GEMM1: Gq = x[qstart:qstart+QROWS] @ [w_w;wz_w;wh_w]^T   (M=2048, N=16896, K=2048)
    gemm_bt<true><<<dim3(NW3/128, QROWS/128), 256, 0, stream>>>(
        xb + (size_t)qstart*DIM, DIM, w3b, DIM, Gq, NW3, DIM);

    // chunked scan with fused causal conv + gating
    scan_chunk  <<<dim3(HID/256, NCHUNKQ), 256, 0, stream>>>(Gq, qstart, zprev, convw, cu, ncu, Ach, Bch);
    scan_combine<<<HID/256, 256, 0, stream>>>(Ach, Bch, Hin, Sc, q == 0 ? 1 : 0);
    scan_final  <<<dim3(HID/256, NCHUNKQ), 256, 0, stream>>>(Gq, qstart, zprev, convw, cu, ncu, Hin);

    // save conv taps for next quarter (z section is never modified above)
    save_ztail<<<(3*HID+255)/256, 256, 0, stream>>>(Gq, zprev);

    // GEMM2: out[qstart:...] = hh @ wo^T  (hh aliased over TH section, lda=NW3; M=2048, N=2048, K=5632)
    gemm_bt<false><<<dim3(DIM/128, QROWS/128), 256, 0, stream>>>(
        Gq + 2*HID, NW3, wob, HID, out + (size_t)qstart*DIM, DIM, HID);
  }
}

// Round 3
// 1808.300 us; speedup vs baseline: 1.1114x; 1.1114x over previous
//
#include <hip/hip_runtime.h>
#include <stdint.h>

#define DIM 2048
#define HID 5632
#define SEQ 8192
#define NW3 (3*HID)            // 16896
#define CONV 4
#define QROWS 2048             // rows per streamed quarter
#define NQ (SEQ/QROWS)         // 4
#define CHUNK 64
#define NCHUNKQ (QROWS/CHUNK)  // 32
#define KSPLIT 4
#define KSLICE (HID/KSPLIT)    // 1408

typedef __attribute__((ext_vector_type(8))) __bf16 bf16x8;
typedef __attribute__((ext_vector_type(4))) float f32x4;

__device__ __forceinline__ uint16_t f2bf(float f) {
  union { float f; uint32_t u; } v; v.f = f;
  return (uint16_t)((v.u + 0x7FFFu + ((v.u >> 16) & 1u)) >> 16);
}
__device__ __forceinline__ float bf2f(uint16_t h) {
  union { uint32_t u; float f; } v; v.u = ((uint32_t)h) << 16;
  return v.f;
}

// ---------------- fp32 -> bf16 conversion (vectorized x4) ----------------
__global__ void cvt4_kernel(const float* __restrict__ src, uint16_t* __restrict__ dst, int n4) {
  int i = blockIdx.x * blockDim.x + threadIdx.x;
  if (i >= n4) return;
  float4 v = ((const float4*)src)[i];
  ushort4 o;
  o.x = f2bf(v.x); o.y = f2bf(v.y); o.z = f2bf(v.z); o.w = f2bf(v.w);
  ((ushort4*)dst)[i] = o;
}

// ---------------- m97-style bf16 GEMM: C = A(M,K;LDA) * B(N,K;LDB)^T ----------------
// OUT_MODE: 0 = fp32 store, 1 = bf16 store, 2 = fp32 atomicAdd (split-K)
__device__ __forceinline__ void load_lds16(const void* g, void* l) {
  __builtin_amdgcn_global_load_lds(
      (__attribute__((address_space(1))) void*)g,
      (__attribute__((address_space(3))) void*)l, 16, 0, 0);
}

template<int LDA, int LDB, int LDC, int KLEN, int OUT_MODE>
__global__ __launch_bounds__(256)
void gemm_bt(const uint16_t* __restrict__ A, const uint16_t* __restrict__ B,
             void* __restrict__ C)
{
  __shared__ uint16_t As[128*32];
  __shared__ uint16_t Bs[128*32];
  const int tid  = threadIdx.x;
  const int wave = tid >> 6;
  const int lane = tid & 63;
  // blockIdx.x = row-block (fastest-varying -> consecutive blocks share a B tile)
  const int row0 = blockIdx.x * 128;
  const int col0 = blockIdx.y * 128;
  const int koff = blockIdx.z * KLEN;   // split-K slice offset (0 when gridDim.z==1)
  const int wm = (wave & 1) * 64;
  const int wn = (wave >> 1) * 64;

  f32x4 acc[4][4];
  #pragma unroll
  for (int i=0;i<4;i++)
    #pragma unroll
    for (int j=0;j<4;j++) acc[i][j] = (f32x4){0.f,0.f,0.f,0.f};

  // staging map: lds elem = (wave*2+q)*512 + lane*8 holds row m=(wave*32+q*16+lane/4), k=(lane%4)*8..+8
  const int mA0 = wave*32 + (lane >> 2);
  const int kkl = (lane & 3) * 8;
  const int kq  = (lane >> 4) * 8;
  const int rm  = lane & 15;

  const uint16_t* Ab = A + (size_t)koff;
  const uint16_t* Bb = B + (size_t)koff;

  for (int k0 = 0; k0 < KLEN; k0 += 32) {
    __syncthreads();
    #pragma unroll
    for (int q = 0; q < 2; ++q) {
      int m = mA0 + q*16;
      load_lds16(Ab + (size_t)(row0 + m)*LDA + k0 + kkl, &As[(size_t)(wave*2+q)*512]);
      load_lds16(Bb + (size_t)(col0 + m)*LDB + k0 + kkl, &Bs[(size_t)(wave*2+q)*512]);
    }
    __syncthreads();
    bf16x8 af[4], bfr[4];
    #pragma unroll
    for (int i=0;i<4;i++) {
      af[i]  = *(const bf16x8*)&As[(wm + i*16 + rm)*32 + kq];
      bfr[i] = *(const bf16x8*)&Bs[(wn + i*16 + rm)*32 + kq];
    }
    #pragma unroll
    for (int i=0;i<4;i++)
      #pragma unroll
      for (int j=0;j<4;j++)
        acc[i][j] = __builtin_amdgcn_mfma_f32_16x16x32_bf16(af[i], bfr[j], acc[i][j], 0, 0, 0);
  }

  const int cr = (lane >> 4) * 4;  // C/D: col = lane&15, row = (lane>>4)*4 + reg
  const int cc = lane & 15;
  #pragma unroll
  for (int i=0;i<4;i++)
    #pragma unroll
    for (int j=0;j<4;j++) {
      int rb = row0 + wm + i*16 + cr;
      int c  = col0 + wn + j*16 + cc;
      #pragma unroll
      for (int r=0;r<4;r++) {
        float v = acc[i][j][r];
        size_t idx = (size_t)(rb+r)*LDC + c;
        if (OUT_MODE == 1)      ((uint16_t*)C)[idx] = f2bf(v);
        else if (OUT_MODE == 2) atomicAdd((float*)C + idx, v);
        else                    ((float*)C)[idx] = v;
      }
    }
}

// ---------------- segment helpers ----------------
// Gq layout per local row r (stride NW3): [0,HID)=w0, [HID,2HID)=z_pre, [2HID,3HID)=tilde_h

__device__ __forceinline__ void seg_info(const int* cuv, int ns, int t, int& ss, bool& st) {
  ss = 0; st = false;
  for (int i=0;i<ns;i++) { int cv = cuv[i]; if (cv<=t && cv>ss) ss=cv; if (cv==t) st=true; }
}

// ---------------- scan pass A: per-chunk conv+sigmoid+local scan ----------------
__global__ void scan_chunk(const uint16_t* __restrict__ Gq, int qstart,
                           const uint16_t* __restrict__ zprev,
                           const float* __restrict__ convw,
                           const int* __restrict__ cu, int ncu,
                           float* __restrict__ Ach, float* __restrict__ Bch)
{
  int h = blockIdx.x * blockDim.x + threadIdx.x;
  int c = blockIdx.y;
  if (h >= HID) return;
  const uint16_t* Z  = Gq + HID;
  const uint16_t* TH = Gq + 2*HID;
  float w0c = convw[h*4+0], w1c = convw[h*4+1], w2c = convw[h*4+2], w3c = convw[h*4+3];
  int cuv[8];
  int ns = ncu - 1; if (ns > 8) ns = 8;
  for (int i=0;i<ns;i++) cuv[i] = cu[i];
  int r0 = c * CHUNK;
  int t0 = qstart + r0;
  float z1, z2, z3;
  if (c == 0) {
    z1 = (t0-1 >= 0) ? bf2f(zprev[2*HID + h]) : 0.f;
    z2 = (t0-2 >= 0) ? bf2f(zprev[1*HID + h]) : 0.f;
    z3 = (t0-3 >= 0) ? bf2f(zprev[0*HID + h]) : 0.f;
  } else {
    z1 = bf2f(Z[(size_t)(r0-1)*NW3 + h]);
    z2 = bf2f(Z[(size_t)(r0-2)*NW3 + h]);
    z3 = bf2f(Z[(size_t)(r0-3)*NW3 + h]);
  }
  float Aacc = 1.f, Bacc = 0.f;
  for (int r = r0; r < r0 + CHUNK; ++r) {
    int t = qstart + r;
    float z0 = bf2f(Z[(size_t)r*NW3 + h]);
    float th = bf2f(TH[(size_t)r*NW3 + h]);
    int ss; bool st;
    seg_info(cuv, ns, t, ss, st);
    float s = z0*w3c;
    if (t-1 >= ss) s += z1*w2c;
    if (t-2 >= ss) s += z2*w1c;
    if (t-3 >= ss) s += z3*w0c;
    float zc = 1.f/(1.f + __expf(-s));
    float a = st ? 0.f : (1.f - zc);
    float b = zc * th;
    Aacc *= a;
    Bacc = a*Bacc + b;
    z3 = z2; z2 = z1; z1 = z0;
  }
  Ach[(size_t)c*HID + h] = Aacc;
  Bch[(size_t)c*HID + h] = Bacc;
}

// ---------------- scan pass B: combine chunk pairs, carry state across quarters ----------------
__global__ void scan_combine(const float* __restrict__ Ach, const float* __restrict__ Bch,
                             float* __restrict__ Hin, float* __restrict__ Sc, int first)
{
  int h = blockIdx.x * blockDim.x + threadIdx.x;
  if (h >= HID) return;
  float s = first ? 0.f : Sc[h];
  for (int c = 0; c < NCHUNKQ; ++c) {
    Hin[(size_t)c*HID + h] = s;
    s = Ach[(size_t)c*HID + h]*s + Bch[(size_t)c*HID + h];
  }
  Sc[h] = s;
}

// ---------------- scan pass C: fixup + h*silu(w0), hh written in place over TH ----------------
__global__ void scan_final(uint16_t* __restrict__ Gq, int qstart,
                           const uint16_t* __restrict__ zprev,
                           const float* __restrict__ convw,
                           const int* __restrict__ cu, int ncu,
                           const float* __restrict__ Hin)
{
  int h = blockIdx.x * blockDim.x + threadIdx.x;
  int c = blockIdx.y;
  if (h >= HID) return;
  const uint16_t* W0 = Gq;
  const uint16_t* Z  = Gq + HID;
  uint16_t*       TH = Gq + 2*HID;     // read th, then overwrite with hh
  float w0c = convw[h*4+0], w1c = convw[h*4+1], w2c = convw[h*4+2], w3c = convw[h*4+3];
  int cuv[8];
  int ns = ncu - 1; if (ns > 8) ns = 8;
  for (int i=0;i<ns;i++) cuv[i] = cu[i];
  int r0 = c * CHUNK;
  int t0 = qstart + r0;
  float z1, z2, z3;
  if (c == 0) {
    z1 = (t0-1 >= 0) ? bf2f(zprev[2*HID + h]) : 0.f;
    z2 = (t0-2 >= 0) ? bf2f(zprev[1*HID + h]) : 0.f;
    z3 = (t0-3 >= 0) ? bf2f(zprev[0*HID + h]) : 0.f;
  } else {
    z1 = bf2f(Z[(size_t)(r0-1)*NW3 + h]);
    z2 = bf2f(Z[(size_t)(r0-2)*NW3 + h]);
    z3 = bf2f(Z[(size_t)(r0-3)*NW3 + h]);
  }
  float state = Hin[(size_t)c*HID + h];
  for (int r = r0; r < r0 + CHUNK; ++r) {
    int t = qstart + r;
    float z0 = bf2f(Z[(size_t)r*NW3 + h]);
    float th = bf2f(TH[(size_t)r*NW3 + h]);
    int ss; bool st;
    seg_info(cuv, ns, t, ss, st);
    float s = z0*w3c;
    if (t-1 >= ss) s += z1*w2c;
    if (t-2 >= ss) s += z2*w1c;
    if (t-3 >= ss) s += z3*w0c;
    float zc = 1.f/(1.f + __expf(-s));
    float a = st ? 0.f : (1.f - zc);
    float b = zc * th;
    state = a*state + b;
    float w0v = bf2f(W0[(size_t)r*NW3 + h]);
    float silu = w0v / (1.f + __expf(-w0v));
    TH[(size_t)r*NW3 + h] = f2bf(state * silu);
    z3 = z2; z2 = z1; z1 = z0;
  }
}

// ---------------- save last 3 z-rows of this quarter for next quarter's conv taps ----------------
__global__ void save_ztail(const uint16_t* __restrict__ Gq, uint16_t* __restrict__ zprev) {
  int i = blockIdx.x * blockDim.x + threadIdx.x;
  if (i >= 3*HID) return;
  int j = i / HID;        // 0,1,2 -> rows QROWS-3+j
  int h = i - j*HID;
  zprev[i] = Gq[(size_t)(QROWS-3+j)*NW3 + HID + h];
}

// ---------------- launcher ----------------
extern "C" void kernel_launch(void* const* d_in, const int* in_sizes, int n_in,
                              void* d_out, int out_size, void* d_ws, size_t ws_size,
                              hipStream_t stream) {
  const float* x     = (const float*)d_in[0];
  const int*   cu    = (const int*)d_in[1];
  const float* w_w   = (const float*)d_in[2];
  const float* wz_w  = (const float*)d_in[3];
  const float* wh_w  = (const float*)d_in[4];
  const float* wo_w  = (const float*)d_in[5];
  const float* convw = (const float*)d_in[6];
  const int ncu = in_sizes[1];
  float* out = (float*)d_out;

  // workspace layout (~197 MB total)
  char* p = (char*)d_ws;
  uint16_t* xb    = (uint16_t*)p; p += (size_t)SEQ*DIM*2;        // 33.5 MB
  uint16_t* w3b   = (uint16_t*)p; p += (size_t)NW3*DIM*2;        // 69.2 MB
  uint16_t* wob   = (uint16_t*)p; p += (size_t)DIM*HID*2;        // 23.1 MB
  uint16_t* Gq    = (uint16_t*)p; p += (size_t)QROWS*NW3*2;      // 69.2 MB
  float* Ach  = (float*)p; p += (size_t)NCHUNKQ*HID*4;           // 0.72 MB
  float* Bch  = (float*)p; p += (size_t)NCHUNKQ*HID*4;
  float* Hin  = (float*)p; p += (size_t)NCHUNKQ*HID*4;
  float* Sc   = (float*)p; p += (size_t)HID*4;                   // 22.5 KB
  uint16_t* zprev = (uint16_t*)p; p += (size_t)3*HID*2;          // 34 KB

  // zero d_out for split-K atomic accumulation (capture-legal memset node)
  hipMemsetAsync(out, 0, (size_t)out_size * sizeof(float), stream);

  // fp32 -> bf16 conversions
  {
    int n4;
    n4 = SEQ*DIM/4;  cvt4_kernel<<<(n4+255)/256, 256, 0, stream>>>(x, xb, n4);
    n4 = HID*DIM/4;  cvt4_kernel<<<(n4+255)/256, 256, 0, stream>>>(w_w,  w3b, n4);
                     cvt4_kernel<<<(n4+255)/256, 256, 0, stream>>>(wz_w, w3b + (size_t)HID*DIM, n4);
                     cvt4_kernel<<<(n4+255)/256, 256, 0, stream>>>(wh_w, w3b + (size_t)2*HID*DIM, n4);
    n4 = DIM*HID/4;  cvt4_kernel<<<(n4+255)/256, 256, 0, stream>>>(wo_w, wob, n4);
  }

  for (int q = 0; q < NQ; ++q) {
    const int qstart = q * QROWS;
    // GEMM1: Gq = x[qstart:+QROWS] @ [w_w;wz_w;wh_w]^T  (M=2048, N=16896, K=2048)
    // grid.x = row-blocks (fastest) so consecutive blocks reuse one B tile from L2
    gemm_bt<DIM, DIM, NW3, DIM, 1><<<dim3(QROWS/128, NW3/128), 256, 0, stream>>>(
        xb + (size_t)qstart*DIM, w3b, Gq);

    // chunked scan with fused causal conv + gating
    scan_chunk  <<<dim3(HID/256, NCHUNKQ), 256, 0, stream>>>(Gq, qstart, zprev, convw, cu, ncu, Ach, Bch);
    scan_combine<<<HID/256, 256, 0, stream>>>(Ach, Bch, Hin, Sc, q == 0 ? 1 : 0);
    scan_final  <<<dim3(HID/256, NCHUNKQ), 256, 0, stream>>>(Gq, qstart, zprev, convw, cu, ncu, Hin);

    // save conv taps for next quarter (z section is never modified above)
    save_ztail<<<(3*HID+255)/256, 256, 0, stream>>>(Gq, zprev);

    // GEMM2: out[qstart:...] += hh @ wo^T  (hh aliased over TH, lda=NW3; M=2048, N=2048, K=5632)
    // split-K=4 (blockIdx.z) -> 1024 blocks for occupancy; fp32 atomicAdd epilogue
    gemm_bt<NW3, HID, DIM, KSLICE, 2><<<dim3(QROWS/128, DIM/128, KSPLIT), 256, 0, stream>>>(
        Gq + 2*HID, wob, out + (size_t)qstart*DIM);
  }
}

// Round 4
// 1601.496 us; speedup vs baseline: 1.2549x; 1.1291x over previous
//
#include <hip/hip_runtime.h>
#include <stdint.h>

#define DIM 2048
#define HID 5632
#define SEQ 8192
#define NW3 (3*HID)            // 16896
#define CONV 4
#define CHUNK 64
#define KSPLIT 4
#define KSLICE (HID/KSPLIT)    // 1408

typedef __attribute__((ext_vector_type(8))) __bf16 bf16x8;
typedef __attribute__((ext_vector_type(4))) float f32x4;

__device__ __forceinline__ uint16_t f2bf(float f) {
  union { float f; uint32_t u; } v; v.f = f;
  return (uint16_t)((v.u + 0x7FFFu + ((v.u >> 16) & 1u)) >> 16);
}
__device__ __forceinline__ float bf2f(uint16_t h) {
  union { uint32_t u; float f; } v; v.u = ((uint32_t)h) << 16;
  return v.f;
}

// ---------------- fp32 -> bf16 conversion (vectorized x4) ----------------
__global__ void cvt4_kernel(const float* __restrict__ src, uint16_t* __restrict__ dst, int n4) {
  int i = blockIdx.x * blockDim.x + threadIdx.x;
  if (i >= n4) return;
  float4 v = ((const float4*)src)[i];
  ushort4 o;
  o.x = f2bf(v.x); o.y = f2bf(v.y); o.z = f2bf(v.z); o.w = f2bf(v.w);
  ((ushort4*)dst)[i] = o;
}

// ---------------- m97-style bf16 GEMM: C = A(M,K;LDA) * B(N,K;LDB)^T ----------------
// OUT_MODE: 0 = fp32 store, 1 = bf16 store, 2 = fp32 atomicAdd (split-K)
// SWAPXY: false -> blockIdx.x = row-block (rows fastest); true -> blockIdx.x = col-block
__device__ __forceinline__ void load_lds16(const void* g, void* l) {
  __builtin_amdgcn_global_load_lds(
      (__attribute__((address_space(1))) void*)g,
      (__attribute__((address_space(3))) void*)l, 16, 0, 0);
}

template<int LDA, int LDB, int LDC, int KLEN, int OUT_MODE, bool SWAPXY>
__global__ __launch_bounds__(256)
void gemm_bt(const uint16_t* __restrict__ A, const uint16_t* __restrict__ B,
             void* __restrict__ C)
{
  __shared__ uint16_t As[128*32];
  __shared__ uint16_t Bs[128*32];
  const int tid  = threadIdx.x;
  const int wave = tid >> 6;
  const int lane = tid & 63;
  const int row0 = (SWAPXY ? blockIdx.y : blockIdx.x) * 128;
  const int col0 = (SWAPXY ? blockIdx.x : blockIdx.y) * 128;
  const int koff = blockIdx.z * KLEN;   // split-K slice offset (0 when gridDim.z==1)
  const int wm = (wave & 1) * 64;
  const int wn = (wave >> 1) * 64;

  f32x4 acc[4][4];
  #pragma unroll
  for (int i=0;i<4;i++)
    #pragma unroll
    for (int j=0;j<4;j++) acc[i][j] = (f32x4){0.f,0.f,0.f,0.f};

  // staging map: lds elem = (wave*2+q)*512 + lane*8 holds row m=(wave*32+q*16+lane/4), k=(lane%4)*8..+8
  const int mA0 = wave*32 + (lane >> 2);
  const int kkl = (lane & 3) * 8;
  const int kq  = (lane >> 4) * 8;
  const int rm  = lane & 15;

  const uint16_t* Ab = A + (size_t)koff;
  const uint16_t* Bb = B + (size_t)koff;

  for (int k0 = 0; k0 < KLEN; k0 += 32) {
    __syncthreads();
    #pragma unroll
    for (int q = 0; q < 2; ++q) {
      int m = mA0 + q*16;
      load_lds16(Ab + (size_t)(row0 + m)*LDA + k0 + kkl, &As[(size_t)(wave*2+q)*512]);
      load_lds16(Bb + (size_t)(col0 + m)*LDB + k0 + kkl, &Bs[(size_t)(wave*2+q)*512]);
    }
    __syncthreads();
    bf16x8 af[4], bfr[4];
    #pragma unroll
    for (int i=0;i<4;i++) {
      af[i]  = *(const bf16x8*)&As[(wm + i*16 + rm)*32 + kq];
      bfr[i] = *(const bf16x8*)&Bs[(wn + i*16 + rm)*32 + kq];
    }
    #pragma unroll
    for (int i=0;i<4;i++)
      #pragma unroll
      for (int j=0;j<4;j++)
        acc[i][j] = __builtin_amdgcn_mfma_f32_16x16x32_bf16(af[i], bfr[j], acc[i][j], 0, 0, 0);
  }

  const int cr = (lane >> 4) * 4;  // C/D: col = lane&15, row = (lane>>4)*4 + reg
  const int cc = lane & 15;
  #pragma unroll
  for (int i=0;i<4;i++)
    #pragma unroll
    for (int j=0;j<4;j++) {
      int rb = row0 + wm + i*16 + cr;
      int c  = col0 + wn + j*16 + cc;
      #pragma unroll
      for (int r=0;r<4;r++) {
        float v = acc[i][j][r];
        size_t idx = (size_t)(rb+r)*LDC + c;
        if (OUT_MODE == 1)      ((uint16_t*)C)[idx] = f2bf(v);
        else if (OUT_MODE == 2) atomicAdd((float*)C + idx, v);
        else                    ((float*)C)[idx] = v;
      }
    }
}

// ---------------- segment helpers ----------------
// G layout per local row r (stride NW3): [0,HID)=w0, [HID,2HID)=z_pre, [2HID,3HID)=tilde_h

__device__ __forceinline__ void seg_info(const int* cuv, int ns, int t, int& ss, bool& st) {
  ss = 0; st = false;
  for (int i=0;i<ns;i++) { int cv = cuv[i]; if (cv<=t && cv>ss) ss=cv; if (cv==t) st=true; }
}

// ---------------- scan pass A: per-chunk conv+sigmoid+local scan ----------------
__global__ void scan_chunk(const uint16_t* __restrict__ G, int qstart,
                           const uint16_t* __restrict__ zprev,
                           const float* __restrict__ convw,
                           const int* __restrict__ cu, int ncu,
                           float* __restrict__ Ach, float* __restrict__ Bch)
{
  int h = blockIdx.x * blockDim.x + threadIdx.x;
  int c = blockIdx.y;
  if (h >= HID) return;
  const uint16_t* Z  = G + HID;
  const uint16_t* TH = G + 2*HID;
  float w0c = convw[h*4+0], w1c = convw[h*4+1], w2c = convw[h*4+2], w3c = convw[h*4+3];
  int cuv[8];
  int ns = ncu - 1; if (ns > 8) ns = 8;
  for (int i=0;i<ns;i++) cuv[i] = cu[i];
  int r0 = c * CHUNK;
  int t0 = qstart + r0;
  float z1, z2, z3;
  if (c == 0) {
    z1 = (t0-1 >= 0) ? bf2f(zprev[2*HID + h]) : 0.f;
    z2 = (t0-2 >= 0) ? bf2f(zprev[1*HID + h]) : 0.f;
    z3 = (t0-3 >= 0) ? bf2f(zprev[0*HID + h]) : 0.f;
  } else {
    z1 = bf2f(Z[(size_t)(r0-1)*NW3 + h]);
    z2 = bf2f(Z[(size_t)(r0-2)*NW3 + h]);
    z3 = bf2f(Z[(size_t)(r0-3)*NW3 + h]);
  }
  float Aacc = 1.f, Bacc = 0.f;
  for (int r = r0; r < r0 + CHUNK; ++r) {
    int t = qstart + r;
    float z0 = bf2f(Z[(size_t)r*NW3 + h]);
    float th = bf2f(TH[(size_t)r*NW3 + h]);
    int ss; bool st;
    seg_info(cuv, ns, t, ss, st);
    float s = z0*w3c;
    if (t-1 >= ss) s += z1*w2c;
    if (t-2 >= ss) s += z2*w1c;
    if (t-3 >= ss) s += z3*w0c;
    float zc = 1.f/(1.f + __expf(-s));
    float a = st ? 0.f : (1.f - zc);
    float b = zc * th;
    Aacc *= a;
    Bacc = a*Bacc + b;
    z3 = z2; z2 = z1; z1 = z0;
  }
  Ach[(size_t)c*HID + h] = Aacc;
  Bch[(size_t)c*HID + h] = Bacc;
}

// ---------------- scan pass B: combine chunk pairs; Hin written in place over Ach ----------------
__global__ void scan_combine(float* __restrict__ Ach, const float* __restrict__ Bch,
                             float* __restrict__ Sc, int first, int nchunk)
{
  int h = blockIdx.x * blockDim.x + threadIdx.x;
  if (h >= HID) return;
  float s = first ? 0.f : Sc[h];
  for (int c = 0; c < nchunk; ++c) {
    size_t idx = (size_t)c*HID + h;
    float a = Ach[idx], b = Bch[idx];
    Ach[idx] = s;                  // state entering chunk c (Hin)
    s = a*s + b;
  }
  Sc[h] = s;
}

// ---------------- scan pass C: fixup + h*silu(w0), hh written in place over TH ----------------
__global__ void scan_final(uint16_t* __restrict__ G, int qstart,
                           const uint16_t* __restrict__ zprev,
                           const float* __restrict__ convw,
                           const int* __restrict__ cu, int ncu,
                           const float* __restrict__ Hin)
{
  int h = blockIdx.x * blockDim.x + threadIdx.x;
  int c = blockIdx.y;
  if (h >= HID) return;
  const uint16_t* W0 = G;
  const uint16_t* Z  = G + HID;
  uint16_t*       TH = G + 2*HID;     // read th, then overwrite with hh
  float w0c = convw[h*4+0], w1c = convw[h*4+1], w2c = convw[h*4+2], w3c = convw[h*4+3];
  int cuv[8];
  int ns = ncu - 1; if (ns > 8) ns = 8;
  for (int i=0;i<ns;i++) cuv[i] = cu[i];
  int r0 = c * CHUNK;
  int t0 = qstart + r0;
  float z1, z2, z3;
  if (c == 0) {
    z1 = (t0-1 >= 0) ? bf2f(zprev[2*HID + h]) : 0.f;
    z2 = (t0-2 >= 0) ? bf2f(zprev[1*HID + h]) : 0.f;
    z3 = (t0-3 >= 0) ? bf2f(zprev[0*HID + h]) : 0.f;
  } else {
    z1 = bf2f(Z[(size_t)(r0-1)*NW3 + h]);
    z2 = bf2f(Z[(size_t)(r0-2)*NW3 + h]);
    z3 = bf2f(Z[(size_t)(r0-3)*NW3 + h]);
  }
  float state = Hin[(size_t)c*HID + h];
  for (int r = r0; r < r0 + CHUNK; ++r) {
    int t = qstart + r;
    float z0 = bf2f(Z[(size_t)r*NW3 + h]);
    float th = bf2f(TH[(size_t)r*NW3 + h]);
    int ss; bool st;
    seg_info(cuv, ns, t, ss, st);
    float s = z0*w3c;
    if (t-1 >= ss) s += z1*w2c;
    if (t-2 >= ss) s += z2*w1c;
    if (t-3 >= ss) s += z3*w0c;
    float zc = 1.f/(1.f + __expf(-s));
    float a = st ? 0.f : (1.f - zc);
    float b = zc * th;
    state = a*state + b;
    float w0v = bf2f(W0[(size_t)r*NW3 + h]);
    float silu = w0v / (1.f + __expf(-w0v));
    TH[(size_t)r*NW3 + h] = f2bf(state * silu);
    z3 = z2; z2 = z1; z1 = z0;
  }
}

// ---------------- save last 3 z-rows of this segment for next segment's conv taps ----------------
__global__ void save_ztail(const uint16_t* __restrict__ G, uint16_t* __restrict__ zprev, int qrows) {
  int i = blockIdx.x * blockDim.x + threadIdx.x;
  if (i >= 3*HID) return;
  int j = i / HID;        // 0,1,2 -> rows qrows-3+j
  int h = i - j*HID;
  zprev[i] = G[(size_t)(qrows-3+j)*NW3 + HID + h];
}

// ---------------- launcher ----------------
extern "C" void kernel_launch(void* const* d_in, const int* in_sizes, int n_in,
                              void* d_out, int out_size, void* d_ws, size_t ws_size,
                              hipStream_t stream) {
  const float* x     = (const float*)d_in[0];
  const int*   cu    = (const int*)d_in[1];
  const float* w_w   = (const float*)d_in[2];
  const float* wz_w  = (const float*)d_in[3];
  const float* wh_w  = (const float*)d_in[4];
  const float* wo_w  = (const float*)d_in[5];
  const float* wo    = (const float*)d_in[5];
  const float* convw = (const float*)d_in[6];
  const int ncu = in_sizes[1];
  float* out = (float*)d_out;
  (void)wo;

  // ---- tier selection: largest segment that fits ws ----
  // per-row bytes: G 33792 + xseg 4096 + Ach/Bch 704 = 38592
  // base: w3b 69,206,016 + wob 23,068,672 + Sc 22,528 + zprev 33,792 = 92,331,008
  const size_t base = 92331008ull;
  int qrows = 2048;
  if (ws_size >= base + 8192ull*38592ull) qrows = 8192;        // 408.5 MB
  else if (ws_size >= base + 4096ull*38592ull) qrows = 4096;   // 250.4 MB
  const int nq = SEQ / qrows;
  const int nchunk = qrows / CHUNK;

  // ---- workspace layout ----
  char* p = (char*)d_ws;
  uint16_t* w3b  = (uint16_t*)p; p += (size_t)NW3*DIM*2;       // 69.2 MB
  uint16_t* wob  = (uint16_t*)p; p += (size_t)DIM*HID*2;       // 23.1 MB
  float*    Sc   = (float*)p;    p += (size_t)HID*4;
  uint16_t* zprev= (uint16_t*)p; p += (size_t)3*HID*2;
  uint16_t* xseg = (uint16_t*)p; p += (size_t)qrows*DIM*2;
  uint16_t* G    = (uint16_t*)p; p += (size_t)qrows*NW3*2;
  float*    Ach  = (float*)p;    p += (size_t)nchunk*HID*4;    // doubles as Hin
  float*    Bch  = (float*)p;    p += (size_t)nchunk*HID*4;

  // ---- weight conversions (once) ----
  {
    int n4 = HID*DIM/4;
    cvt4_kernel<<<(n4+255)/256, 256, 0, stream>>>(w_w,  w3b, n4);
    cvt4_kernel<<<(n4+255)/256, 256, 0, stream>>>(wz_w, w3b + (size_t)HID*DIM, n4);
    cvt4_kernel<<<(n4+255)/256, 256, 0, stream>>>(wh_w, w3b + (size_t)2*HID*DIM, n4);
    n4 = DIM*HID/4;
    cvt4_kernel<<<(n4+255)/256, 256, 0, stream>>>(wo_w, wob, n4);
  }

  if (qrows == 2048)  // split-K atomics epilogue needs zeroed out
    hipMemsetAsync(out, 0, (size_t)out_size * sizeof(float), stream);

  for (int s = 0; s < nq; ++s) {
    const int qstart = s * qrows;

    // x segment -> bf16
    int n4 = qrows*DIM/4;
    cvt4_kernel<<<(n4+255)/256, 256, 0, stream>>>(x + (size_t)qstart*DIM, xseg, n4);

    // GEMM1: G = xseg @ [w_w;wz_w;wh_w]^T  (M=qrows, N=16896, K=2048), rows fastest
    gemm_bt<DIM, DIM, NW3, DIM, 1, false><<<dim3(qrows/128, NW3/128), 256, 0, stream>>>(
        xseg, w3b, G);

    // chunked scan with fused causal conv + gating
    scan_chunk  <<<dim3(HID/256, nchunk), 256, 0, stream>>>(G, qstart, zprev, convw, cu, ncu, Ach, Bch);
    scan_combine<<<HID/256, 256, 0, stream>>>(Ach, Bch, Sc, s == 0 ? 1 : 0, nchunk);
    scan_final  <<<dim3(HID/256, nchunk), 256, 0, stream>>>(G, qstart, zprev, convw, cu, ncu, Ach);

    if (s + 1 < nq)
      save_ztail<<<(3*HID+255)/256, 256, 0, stream>>>(G, zprev, qrows);

    // GEMM2: out[qstart:] = hh @ wo^T  (hh aliased over TH, lda=NW3; N=2048, K=5632)
    if (qrows == 2048) {
      // quarter fallback: split-K=4 + atomics (known-good r3 path)
      gemm_bt<NW3, HID, DIM, KSLICE, 2, true><<<dim3(DIM/128, qrows/128, KSPLIT), 256, 0, stream>>>(
          G + 2*HID, wob, out + (size_t)qstart*DIM);
    } else {
      // clean single GEMM, cols fastest (B reuse + A row-panel locality)
      gemm_bt<NW3, HID, DIM, HID, 0, true><<<dim3(DIM/128, qrows/128), 256, 0, stream>>>(
          G + 2*HID, wob, out + (size_t)qstart*DIM);
    }
  }
}